// Round 3
// baseline (3599.051 us; speedup 1.0000x reference)
//
#include <hip/hip_runtime.h>

// GCN layer: out = relu( A0 @ (X W0) + A1 @ (X W1) )
//   X: [65536, 128] fp32, W: [128,128] fp32, A*: COO (rows, cols, vals), E=1M each.
// Strategy:
//   1) gemm_xw: H = X @ W  (fp32 vector GEMM, 64x128 tile per block, X tile in LDS)
//   2) spmm_scatter: out[rows[e]] += vals[e] * H[cols[e]]  (fp32 atomics)
//   sequential over the two filters reusing one 32MB H buffer in d_ws,
//   3) relu in place on d_out.

__global__ __launch_bounds__(256) void gemm_xw(const float* __restrict__ X,
                                               const float* __restrict__ W,
                                               float* __restrict__ H) {
    // Each block computes a 64-row x 128-col tile of H.
    __shared__ float4 xs[64][32];             // 32 KB: 64 rows x 128 floats
    const int tid = threadIdx.x;
    const int tx  = tid & 31;                 // col4 index: cols tx*4 .. tx*4+3
    const int ty  = tid >> 5;                 // 0..7
    const long rbase = (long)blockIdx.x * 64;

    // Stage X tile (coalesced float4, conflict-free writes)
    const float4* Xv = reinterpret_cast<const float4*>(X + rbase * 128);
#pragma unroll
    for (int i = 0; i < 8; ++i) {
        int idx = tid + i * 256;              // 0..2047
        xs[idx >> 5][idx & 31] = Xv[idx];
    }
    __syncthreads();

    float acc[8][4];
#pragma unroll
    for (int r = 0; r < 8; ++r)
#pragma unroll
        for (int c = 0; c < 4; ++c) acc[r][c] = 0.0f;

    const float4* Wv = reinterpret_cast<const float4*>(W);

#pragma unroll 1
    for (int k0 = 0; k0 < 32; ++k0) {         // k = 4*k0 .. 4*k0+3
        // W rows k0*4..+3, cols tx*4..+3 (L1/L2 resident, coalesced across tx)
        float4 w0 = Wv[(k0 * 4 + 0) * 32 + tx];
        float4 w1 = Wv[(k0 * 4 + 1) * 32 + tx];
        float4 w2 = Wv[(k0 * 4 + 2) * 32 + tx];
        float4 w3 = Wv[(k0 * 4 + 3) * 32 + tx];
#pragma unroll
        for (int rr = 0; rr < 8; ++rr) {
            int row = rr * 8 + ty;
            // 2 distinct LDS addresses per wave (ty,ty+1) -> 2-way = free
            float4 xv = xs[row][k0];
            acc[rr][0] += xv.x * w0.x + xv.y * w1.x + xv.z * w2.x + xv.w * w3.x;
            acc[rr][1] += xv.x * w0.y + xv.y * w1.y + xv.z * w2.y + xv.w * w3.y;
            acc[rr][2] += xv.x * w0.z + xv.y * w1.z + xv.z * w2.z + xv.w * w3.z;
            acc[rr][3] += xv.x * w0.w + xv.y * w1.w + xv.z * w2.w + xv.w * w3.w;
        }
    }

#pragma unroll
    for (int rr = 0; rr < 8; ++rr) {
        int row = rr * 8 + ty;
        float4 o = make_float4(acc[rr][0], acc[rr][1], acc[rr][2], acc[rr][3]);
        reinterpret_cast<float4*>(H + (rbase + row) * 128)[tx] = o;
    }
}

// 32 lanes per edge, each lane owns a float4 (4 cols). 2 edges per wave.
__global__ __launch_bounds__(256) void spmm_scatter(const int* __restrict__ rows,
                                                    const int* __restrict__ cols,
                                                    const float* __restrict__ vals,
                                                    const float* __restrict__ H,
                                                    float* __restrict__ out, int E) {
    long tid = (long)blockIdx.x * blockDim.x + threadIdx.x;
    int sub  = (int)(tid & 31);
    long e   = tid >> 5;
    if (e >= E) return;
    int   r = rows[e];
    int   c = cols[e];
    float v = vals[e];
    float4 h = *reinterpret_cast<const float4*>(H + (size_t)c * 128 + sub * 4);
    float* o = out + (size_t)r * 128 + sub * 4;
    atomicAdd(o + 0, v * h.x);
    atomicAdd(o + 1, v * h.y);
    atomicAdd(o + 2, v * h.z);
    atomicAdd(o + 3, v * h.w);
}

__global__ __launch_bounds__(256) void relu_inplace(float* __restrict__ out, long n4) {
    long i = (long)blockIdx.x * blockDim.x + threadIdx.x;
    if (i < n4) {
        float4* p = reinterpret_cast<float4*>(out) + i;
        float4 v = *p;
        v.x = fmaxf(v.x, 0.0f);
        v.y = fmaxf(v.y, 0.0f);
        v.z = fmaxf(v.z, 0.0f);
        v.w = fmaxf(v.w, 0.0f);
        *p = v;
    }
}

extern "C" void kernel_launch(void* const* d_in, const int* in_sizes, int n_in,
                              void* d_out, int out_size, void* d_ws, size_t ws_size,
                              hipStream_t stream) {
    const float* X     = (const float*)d_in[0];
    const float* W0    = (const float*)d_in[1];
    const float* W1    = (const float*)d_in[2];
    const int*   rows0 = (const int*)d_in[3];
    const int*   cols0 = (const int*)d_in[4];
    const float* vals0 = (const float*)d_in[5];
    const int*   rows1 = (const int*)d_in[6];
    const int*   cols1 = (const int*)d_in[7];
    const float* vals1 = (const float*)d_in[8];

    float* out = (float*)d_out;
    float* H   = (float*)d_ws;        // 65536 x 128 fp32 = 32 MB

    const int BN = in_sizes[0] / 128; // 65536 rows
    const int E  = in_sizes[3];       // 1048576 edges per filter

    // Output accumulator must start at zero every call (harness poisons once).
    hipMemsetAsync(d_out, 0, (size_t)out_size * sizeof(float), stream);

    const int gemm_blocks = BN / 64;                       // 1024
    const int scat_blocks = (int)(((long)E * 32 + 255) / 256); // 131072
    const long n4 = (long)out_size / 4;
    const int relu_blocks = (int)((n4 + 255) / 256);

    gemm_xw<<<gemm_blocks, 256, 0, stream>>>(X, W0, H);
    spmm_scatter<<<scat_blocks, 256, 0, stream>>>(rows0, cols0, vals0, H, out, E);

    gemm_xw<<<gemm_blocks, 256, 0, stream>>>(X, W1, H);
    spmm_scatter<<<scat_blocks, 256, 0, stream>>>(rows1, cols1, vals1, H, out, E);

    relu_inplace<<<relu_blocks, 256, 0, stream>>>(out, n4);
}

// Round 4
// 525.386 us; speedup vs baseline: 6.8503x; 6.8503x over previous
//
#include <hip/hip_runtime.h>

// GCN layer: out = relu( A0 @ (X W0) + A1 @ (X W1) )
//   X: [65536,128] fp32, W: [128,128] fp32, A*: COO (rows,cols,vals), E=1M each.
//
// Round 3: replace atomic scatter (atomic-throughput bound, 2 GB HBM RMW/dispatch)
// with CSR-gather:
//   per filter: H = X@W  ->  counting-sort edges by dest row  ->  one half-wave
//   per output row gathers/accumulates in registers, writes out once.
// Filter 0 overwrites out; filter 1 adds + fused relu. No d_out memset needed.

// ---------------- dense GEMM: H = X @ W (fp32 vector ALU) ----------------
__global__ __launch_bounds__(256) void gemm_xw(const float* __restrict__ X,
                                               const float* __restrict__ W,
                                               float* __restrict__ H) {
    __shared__ float4 xs[64][32];             // 64 rows x 128 floats
    const int tid = threadIdx.x;
    const int tx  = tid & 31;                 // col4 index
    const int ty  = tid >> 5;                 // 0..7
    const long rbase = (long)blockIdx.x * 64;

    const float4* Xv = reinterpret_cast<const float4*>(X + rbase * 128);
#pragma unroll
    for (int i = 0; i < 8; ++i) {
        int idx = tid + i * 256;
        xs[idx >> 5][idx & 31] = Xv[idx];
    }
    __syncthreads();

    float acc[8][4];
#pragma unroll
    for (int r = 0; r < 8; ++r)
#pragma unroll
        for (int c = 0; c < 4; ++c) acc[r][c] = 0.0f;

    const float4* Wv = reinterpret_cast<const float4*>(W);

#pragma unroll 1
    for (int k0 = 0; k0 < 32; ++k0) {
        float4 w0 = Wv[(k0 * 4 + 0) * 32 + tx];
        float4 w1 = Wv[(k0 * 4 + 1) * 32 + tx];
        float4 w2 = Wv[(k0 * 4 + 2) * 32 + tx];
        float4 w3 = Wv[(k0 * 4 + 3) * 32 + tx];
#pragma unroll
        for (int rr = 0; rr < 8; ++rr) {
            int row = rr * 8 + ty;
            float4 xv = xs[row][k0];
            acc[rr][0] += xv.x * w0.x + xv.y * w1.x + xv.z * w2.x + xv.w * w3.x;
            acc[rr][1] += xv.x * w0.y + xv.y * w1.y + xv.z * w2.y + xv.w * w3.y;
            acc[rr][2] += xv.x * w0.z + xv.y * w1.z + xv.z * w2.z + xv.w * w3.z;
            acc[rr][3] += xv.x * w0.w + xv.y * w1.w + xv.z * w2.w + xv.w * w3.w;
        }
    }

#pragma unroll
    for (int rr = 0; rr < 8; ++rr) {
        int row = rr * 8 + ty;
        float4 o = make_float4(acc[rr][0], acc[rr][1], acc[rr][2], acc[rr][3]);
        reinterpret_cast<float4*>(H + (rbase + row) * 128)[tx] = o;
    }
}

// ---------------- CSR build: histogram -> scan -> permute ----------------
__global__ __launch_bounds__(256) void hist_rows(const int* __restrict__ rows,
                                                 int* __restrict__ counts, int E) {
    int e = blockIdx.x * 256 + threadIdx.x;
    if (e < E) atomicAdd(&counts[rows[e]], 1);
}

// Single-block exclusive scan of n (=65536) counts.
// counts may alias cursor (same-thread same-address read-then-write is safe).
__global__ __launch_bounds__(256) void scan_counts(const int* __restrict__ counts,
                                                   int* __restrict__ row_ptr,
                                                   int* __restrict__ cursor, int n) {
    __shared__ int ssum[256];
    const int t = threadIdx.x;
    const int chunk = n / 256;                // 256
    const int base = t * chunk;
    const int4* c4 = reinterpret_cast<const int4*>(counts + base);

    int s = 0;
#pragma unroll 4
    for (int i = 0; i < chunk / 4; ++i) {
        int4 v = c4[i];
        s += v.x + v.y + v.z + v.w;
    }
    ssum[t] = s;
    __syncthreads();
    for (int off = 1; off < 256; off <<= 1) {   // inclusive Hillis-Steele
        int u = (t >= off) ? ssum[t - off] : 0;
        __syncthreads();
        ssum[t] += u;
        __syncthreads();
    }
    int run = ssum[t] - s;                      // exclusive base of this chunk

    int4* rp4 = reinterpret_cast<int4*>(row_ptr + base);
    int4* cu4 = reinterpret_cast<int4*>(cursor + base);
#pragma unroll 4
    for (int i = 0; i < chunk / 4; ++i) {
        int4 v = c4[i];
        int4 p;
        p.x = run; run += v.x;
        p.y = run; run += v.y;
        p.z = run; run += v.z;
        p.w = run; run += v.w;
        rp4[i] = p;
        cu4[i] = p;
    }
    if (t == 255) row_ptr[n] = run;             // == E
}

__global__ __launch_bounds__(256) void permute_edges(const int* __restrict__ rows,
                                                     const int* __restrict__ cols,
                                                     const float* __restrict__ vals,
                                                     int* __restrict__ cursor,
                                                     int2* __restrict__ cv, int E) {
    int e = blockIdx.x * 256 + threadIdx.x;
    if (e < E) {
        int r = rows[e];
        int pos = atomicAdd(&cursor[r], 1);
        cv[pos] = make_int2(cols[e], __float_as_int(vals[e]));
    }
}

// ---------------- gather: one half-wave (32 lanes) per output row --------
// MODE 0: out[r] = sum              (overwrite — initializes out)
// MODE 1: out[r] = relu(out[r]+sum) (fused add_n + relu)
template <int MODE>
__global__ __launch_bounds__(256) void spmm_gather(const int* __restrict__ row_ptr,
                                                   const int2* __restrict__ cv,
                                                   const float* __restrict__ H,
                                                   float* __restrict__ out) {
    const int half = threadIdx.x >> 5;          // 0..7: row within block
    const int sub  = threadIdx.x & 31;          // float4 column slot
    const int r = blockIdx.x * 8 + half;
    const int start = row_ptr[r];
    const int end   = row_ptr[r + 1];
    const float4* Hv = reinterpret_cast<const float4*>(H);

    float4 acc = make_float4(0.0f, 0.0f, 0.0f, 0.0f);
    for (int e = start; e < end; ++e) {
        int2 p = cv[e];
        float v = __int_as_float(p.y);
        float4 h = Hv[(size_t)p.x * 32 + sub];
        acc.x = fmaf(v, h.x, acc.x);
        acc.y = fmaf(v, h.y, acc.y);
        acc.z = fmaf(v, h.z, acc.z);
        acc.w = fmaf(v, h.w, acc.w);
    }

    float4* o = reinterpret_cast<float4*>(out) + (size_t)r * 32 + sub;
    if (MODE == 0) {
        *o = acc;
    } else {
        float4 p = *o;
        acc.x = fmaxf(acc.x + p.x, 0.0f);
        acc.y = fmaxf(acc.y + p.y, 0.0f);
        acc.z = fmaxf(acc.z + p.z, 0.0f);
        acc.w = fmaxf(acc.w + p.w, 0.0f);
        *o = acc;
    }
}

extern "C" void kernel_launch(void* const* d_in, const int* in_sizes, int n_in,
                              void* d_out, int out_size, void* d_ws, size_t ws_size,
                              hipStream_t stream) {
    const float* X     = (const float*)d_in[0];
    const float* W0    = (const float*)d_in[1];
    const float* W1    = (const float*)d_in[2];
    const int*   rows0 = (const int*)d_in[3];
    const int*   cols0 = (const int*)d_in[4];
    const float* vals0 = (const float*)d_in[5];
    const int*   rows1 = (const int*)d_in[6];
    const int*   cols1 = (const int*)d_in[7];
    const float* vals1 = (const float*)d_in[8];
    float* out = (float*)d_out;

    const int BN = in_sizes[0] / 128;           // 65536
    const int E  = in_sizes[3];                 // 1048576

    // Workspace layout (all 16B-aligned): H | row_ptr | cursor | cv
    char* ws = (char*)d_ws;
    size_t off = 0;
    float* H = (float*)(ws + off);  off += (size_t)BN * 128 * sizeof(float);     // 32 MB
    int* row_ptr = (int*)(ws + off); off += ((size_t)BN + 4) * sizeof(int);
    off = (off + 15) & ~(size_t)15;
    int* cursor  = (int*)(ws + off); off += (size_t)BN * sizeof(int);
    off = (off + 15) & ~(size_t)15;
    int2* cv     = (int2*)(ws + off);                                            // 8 MB

    const int gemm_blocks = BN / 64;            // 1024
    const int edge_blocks = (E + 255) / 256;    // 4096
    const int gath_blocks = BN / 8;             // 8192

    // ---- filter 0 ----
    gemm_xw<<<gemm_blocks, 256, 0, stream>>>(X, W0, H);
    hipMemsetAsync(cursor, 0, (size_t)BN * sizeof(int), stream);
    hist_rows<<<edge_blocks, 256, 0, stream>>>(rows0, cursor, E);
    scan_counts<<<1, 256, 0, stream>>>(cursor, row_ptr, cursor, BN);
    permute_edges<<<edge_blocks, 256, 0, stream>>>(rows0, cols0, vals0, cursor, cv, E);
    spmm_gather<0><<<gath_blocks, 256, 0, stream>>>(row_ptr, cv, H, out);

    // ---- filter 1 (+ fused relu) ----
    gemm_xw<<<gemm_blocks, 256, 0, stream>>>(X, W1, H);
    hipMemsetAsync(cursor, 0, (size_t)BN * sizeof(int), stream);
    hist_rows<<<edge_blocks, 256, 0, stream>>>(rows1, cursor, E);
    scan_counts<<<1, 256, 0, stream>>>(cursor, row_ptr, cursor, BN);
    permute_edges<<<edge_blocks, 256, 0, stream>>>(rows1, cols1, vals1, cursor, cv, E);
    spmm_gather<1><<<gath_blocks, 256, 0, stream>>>(row_ptr, cv, H, out);
}

// Round 5
// 424.702 us; speedup vs baseline: 8.4743x; 1.2371x over previous
//
#include <hip/hip_runtime.h>

// GCN layer: out = relu( A0 @ (X W0) + A1 @ (X W1) )
//   X: [65536,128] fp32, W: [128,128] fp32, A*: COO (rows,cols,vals), E=1M each.
//
// Round 4 -> 5: bf16 H + packed 4B edges (halve gather/permute traffic),
// fuse both filters into single dispatches (13 -> 6 launches), fused final
// gather computes relu(sum0+sum1) and writes out exactly once.
//
// Pipeline: gemm(both) -> memset cursors -> hist(both) -> scan(2 blk) ->
//           permute(both) -> gather_fused.

typedef unsigned int  uint;
typedef unsigned short ushort;

__device__ __forceinline__ ushort f2bf(float f) {      // fp32 -> bf16 RNE
    uint u = __float_as_uint(f);
    u += 0x7fffu + ((u >> 16) & 1u);
    return (ushort)(u >> 16);
}
__device__ __forceinline__ float bf2f(ushort h) {      // bf16 -> fp32 (exact)
    return __uint_as_float((uint)h << 16);
}

// ---------------- dense GEMM: H_f = X @ W_f, bf16 store -------------------
__global__ __launch_bounds__(256) void gemm_xw_bf16(const float* __restrict__ X,
                                                    const float* __restrict__ W0,
                                                    const float* __restrict__ W1,
                                                    ushort* __restrict__ H, int BN) {
    __shared__ float4 xs[64][32];                     // 64 rows x 128 floats
    const float* W = blockIdx.y ? W1 : W0;
    ushort* Hf = H + (size_t)blockIdx.y * BN * 128;

    const int tid = threadIdx.x;
    const int tx  = tid & 31;                         // col4 index
    const int ty  = tid >> 5;                         // 0..7
    const long rbase = (long)blockIdx.x * 64;

    const float4* Xv = reinterpret_cast<const float4*>(X + rbase * 128);
#pragma unroll
    for (int i = 0; i < 8; ++i) {
        int idx = tid + i * 256;
        xs[idx >> 5][idx & 31] = Xv[idx];
    }
    __syncthreads();

    float acc[8][4];
#pragma unroll
    for (int r = 0; r < 8; ++r)
#pragma unroll
        for (int c = 0; c < 4; ++c) acc[r][c] = 0.0f;

    const float4* Wv = reinterpret_cast<const float4*>(W);

#pragma unroll 1
    for (int k0 = 0; k0 < 32; ++k0) {
        float4 w0 = Wv[(k0 * 4 + 0) * 32 + tx];
        float4 w1 = Wv[(k0 * 4 + 1) * 32 + tx];
        float4 w2 = Wv[(k0 * 4 + 2) * 32 + tx];
        float4 w3 = Wv[(k0 * 4 + 3) * 32 + tx];
#pragma unroll
        for (int rr = 0; rr < 8; ++rr) {
            int row = rr * 8 + ty;
            float4 xv = xs[row][k0];                  // 2 addrs/wave -> free
            acc[rr][0] += xv.x * w0.x + xv.y * w1.x + xv.z * w2.x + xv.w * w3.x;
            acc[rr][1] += xv.x * w0.y + xv.y * w1.y + xv.z * w2.y + xv.w * w3.y;
            acc[rr][2] += xv.x * w0.z + xv.y * w1.z + xv.z * w2.z + xv.w * w3.z;
            acc[rr][3] += xv.x * w0.w + xv.y * w1.w + xv.z * w2.w + xv.w * w3.w;
        }
    }

#pragma unroll
    for (int rr = 0; rr < 8; ++rr) {
        int row = rr * 8 + ty;
        ushort4 o;
        o.x = f2bf(acc[rr][0]); o.y = f2bf(acc[rr][1]);
        o.z = f2bf(acc[rr][2]); o.w = f2bf(acc[rr][3]);
        reinterpret_cast<ushort4*>(Hf + (rbase + row) * 128)[tx] = o;
    }
}

// ---------------- CSR build (both filters) --------------------------------
__global__ __launch_bounds__(256) void hist2(const int* __restrict__ r0,
                                             const int* __restrict__ r1,
                                             int* __restrict__ cnt, int E, int BN) {
    int e = blockIdx.x * 256 + threadIdx.x;
    const int* rows = blockIdx.y ? r1 : r0;
    if (e < E) atomicAdd(&cnt[(size_t)blockIdx.y * BN + rows[e]], 1);
}

// One block per filter: exclusive scan of BN (=65536) counts.
// counts aliases cursor output (same-thread read-then-write is safe).
__global__ __launch_bounds__(256) void scan2(int* __restrict__ cnt,
                                             int* __restrict__ row_ptr,
                                             int n, int rp_stride) {
    __shared__ int ssum[256];
    int* counts = cnt + (size_t)blockIdx.x * n;
    int* rp     = row_ptr + (size_t)blockIdx.x * rp_stride;

    const int t = threadIdx.x;
    const int chunk = n / 256;                        // 256
    const int base = t * chunk;
    const int4* c4 = reinterpret_cast<const int4*>(counts + base);

    int s = 0;
#pragma unroll 4
    for (int i = 0; i < chunk / 4; ++i) {
        int4 v = c4[i];
        s += v.x + v.y + v.z + v.w;
    }
    ssum[t] = s;
    __syncthreads();
    for (int off = 1; off < 256; off <<= 1) {         // inclusive Hillis-Steele
        int u = (t >= off) ? ssum[t - off] : 0;
        __syncthreads();
        ssum[t] += u;
        __syncthreads();
    }
    int run = ssum[t] - s;                            // exclusive chunk base

    int4* rp4 = reinterpret_cast<int4*>(rp + base);
    int4* cu4 = reinterpret_cast<int4*>(counts + base);
#pragma unroll 4
    for (int i = 0; i < chunk / 4; ++i) {
        int4 v = c4[i];
        int4 p;
        p.x = run; run += v.x;
        p.y = run; run += v.y;
        p.z = run; run += v.z;
        p.w = run; run += v.w;
        rp4[i] = p;
        cu4[i] = p;
    }
    if (t == 255) rp[n] = run;                        // == E
}

// Permute edges to dest-row order, packed as (col<<16)|bf16(val).
__global__ __launch_bounds__(256) void permute2(const int* __restrict__ r0,
                                                const int* __restrict__ c0,
                                                const float* __restrict__ v0,
                                                const int* __restrict__ r1,
                                                const int* __restrict__ c1,
                                                const float* __restrict__ v1,
                                                int* __restrict__ cursor,
                                                uint* __restrict__ cv, int E, int BN) {
    int f = blockIdx.y;
    const int*   rows = f ? r1 : r0;
    const int*   cols = f ? c1 : c0;
    const float* vals = f ? v1 : v0;
    int e = blockIdx.x * 256 + threadIdx.x;
    if (e < E) {
        int r = rows[e];
        int pos = atomicAdd(&cursor[(size_t)f * BN + r], 1);
        cv[(size_t)f * E + pos] = ((uint)cols[e] << 16) | (uint)f2bf(vals[e]);
    }
}

// ---------------- fused gather: out[r] = relu(sum_A0 + sum_A1) ------------
// Half-wave (32 lanes) per output row; 2-edge dual-accumulator unroll.
__global__ __launch_bounds__(256) void gather_fused(const int* __restrict__ row_ptr,
                                                    int rp_stride,
                                                    const uint* __restrict__ cv, int E,
                                                    const ushort* __restrict__ H, int BN,
                                                    float* __restrict__ out) {
    const int half = threadIdx.x >> 5;                // 0..7
    const int sub  = threadIdx.x & 31;                // col4 slot
    const int r = blockIdx.x * 8 + half;

    float4 a0 = make_float4(0.f, 0.f, 0.f, 0.f);
    float4 a1 = make_float4(0.f, 0.f, 0.f, 0.f);

#pragma unroll
    for (int f = 0; f < 2; ++f) {
        const int*    rp  = row_ptr + (size_t)f * rp_stride;
        const uint*   cvf = cv + (size_t)f * E;
        const ushort* Hf  = H + (size_t)f * BN * 128;
        const int s = rp[r];
        const int t = rp[r + 1];
        int e = s;
        for (; e + 1 < t; e += 2) {
            uint p0 = cvf[e], p1 = cvf[e + 1];
            float v0 = __uint_as_float(p0 << 16);
            float v1 = __uint_as_float(p1 << 16);
            ushort4 h0 = reinterpret_cast<const ushort4*>(Hf + (size_t)(p0 >> 16) * 128)[sub];
            ushort4 h1 = reinterpret_cast<const ushort4*>(Hf + (size_t)(p1 >> 16) * 128)[sub];
            a0.x = fmaf(v0, bf2f(h0.x), a0.x);
            a0.y = fmaf(v0, bf2f(h0.y), a0.y);
            a0.z = fmaf(v0, bf2f(h0.z), a0.z);
            a0.w = fmaf(v0, bf2f(h0.w), a0.w);
            a1.x = fmaf(v1, bf2f(h1.x), a1.x);
            a1.y = fmaf(v1, bf2f(h1.y), a1.y);
            a1.z = fmaf(v1, bf2f(h1.z), a1.z);
            a1.w = fmaf(v1, bf2f(h1.w), a1.w);
        }
        if (e < t) {
            uint p0 = cvf[e];
            float v0 = __uint_as_float(p0 << 16);
            ushort4 h0 = reinterpret_cast<const ushort4*>(Hf + (size_t)(p0 >> 16) * 128)[sub];
            a0.x = fmaf(v0, bf2f(h0.x), a0.x);
            a0.y = fmaf(v0, bf2f(h0.y), a0.y);
            a0.z = fmaf(v0, bf2f(h0.z), a0.z);
            a0.w = fmaf(v0, bf2f(h0.w), a0.w);
        }
    }

    float4 o;
    o.x = fmaxf(a0.x + a1.x, 0.0f);
    o.y = fmaxf(a0.y + a1.y, 0.0f);
    o.z = fmaxf(a0.z + a1.z, 0.0f);
    o.w = fmaxf(a0.w + a1.w, 0.0f);
    reinterpret_cast<float4*>(out)[(size_t)r * 32 + sub] = o;
}

extern "C" void kernel_launch(void* const* d_in, const int* in_sizes, int n_in,
                              void* d_out, int out_size, void* d_ws, size_t ws_size,
                              hipStream_t stream) {
    const float* X     = (const float*)d_in[0];
    const float* W0    = (const float*)d_in[1];
    const float* W1    = (const float*)d_in[2];
    const int*   rows0 = (const int*)d_in[3];
    const int*   cols0 = (const int*)d_in[4];
    const float* vals0 = (const float*)d_in[5];
    const int*   rows1 = (const int*)d_in[6];
    const int*   cols1 = (const int*)d_in[7];
    const float* vals1 = (const float*)d_in[8];
    float* out = (float*)d_out;

    const int BN = in_sizes[0] / 128;                 // 65536
    const int E  = in_sizes[3];                       // 1048576
    const int rp_stride = BN + 16;

    // Workspace: H[2][BN][128] bf16 | cv[2][E] u32 | row_ptr[2][rp_stride] | cursor[2][BN]
    char* ws = (char*)d_ws;
    size_t off = 0;
    ushort* H = (ushort*)(ws + off); off += (size_t)2 * BN * 128 * sizeof(ushort); // 32 MB
    uint* cv  = (uint*)(ws + off);   off += (size_t)2 * E * sizeof(uint);          // 8 MB
    int* row_ptr = (int*)(ws + off); off += (size_t)2 * rp_stride * sizeof(int);
    int* cursor  = (int*)(ws + off); off += (size_t)2 * BN * sizeof(int);

    const int gemm_blocks = BN / 64;                  // 1024
    const int edge_blocks = (E + 255) / 256;          // 4096
    const int gath_blocks = BN / 8;                   // 8192

    gemm_xw_bf16<<<dim3(gemm_blocks, 2), 256, 0, stream>>>(X, W0, W1, H, BN);
    hipMemsetAsync(cursor, 0, (size_t)2 * BN * sizeof(int), stream);
    hist2<<<dim3(edge_blocks, 2), 256, 0, stream>>>(rows0, rows1, cursor, E, BN);
    scan2<<<2, 256, 0, stream>>>(cursor, row_ptr, BN, rp_stride);
    permute2<<<dim3(edge_blocks, 2), 256, 0, stream>>>(rows0, cols0, vals0,
                                                       rows1, cols1, vals1,
                                                       cursor, cv, E, BN);
    gather_fused<<<gath_blocks, 256, 0, stream>>>(row_ptr, rp_stride, cv, E, H, BN, out);
}

// Round 6
// 212.191 us; speedup vs baseline: 16.9613x; 2.0015x over previous
//
#include <hip/hip_runtime.h>

// GCN layer: out = relu( A0 @ (X W0) + A1 @ (X W1) )
//   X: [65536,128] fp32, W: [128,128] fp32, A*: COO (rows,cols,vals), E=1M each.
//
// Round 6: permute2's random 4B scatter stores were becoming 64B partial-line
// HBM writes (144 MB measured, cross-XCD lines never merge). Replace the
// single-pass 65536-bin scatter with a two-level counting sort whose writes
// are block-chunked (same-line writers = same block/XCD -> L2 write-combine):
//   hist_coarse -> scan_coarse -> partition(256 buckets, per-block chunks)
//   -> bucket_sort(per-bucket 256-row sort, block-local 16KB region, emits
//      row_ptr) -> gather_fused (4-edge unroll).
// Falls back to the round-5 pipeline if ws_size is too small for the extra
// 10.5 MiB of partition buffers.

typedef unsigned int   uint;
typedef unsigned short ushort;
typedef unsigned char  uchar;

constexpr int NB  = 256;   // coarse buckets: row >> 8 (256 rows each, BN=65536)
constexpr int EPB = 8192;  // edges per partition/hist block

__device__ __forceinline__ ushort f2bf(float f) {      // fp32 -> bf16 RNE
    uint u = __float_as_uint(f);
    u += 0x7fffu + ((u >> 16) & 1u);
    return (ushort)(u >> 16);
}
__device__ __forceinline__ float bf2f(ushort h) {      // bf16 -> fp32 (exact)
    return __uint_as_float((uint)h << 16);
}

// ---------------- dense GEMM: H_f = X @ W_f, bf16 store -------------------
__global__ __launch_bounds__(256) void gemm_xw_bf16(const float* __restrict__ X,
                                                    const float* __restrict__ W0,
                                                    const float* __restrict__ W1,
                                                    ushort* __restrict__ H, int BN) {
    __shared__ float4 xs[64][32];                     // 64 rows x 128 floats
    const float* W = blockIdx.y ? W1 : W0;
    ushort* Hf = H + (size_t)blockIdx.y * BN * 128;

    const int tid = threadIdx.x;
    const int tx  = tid & 31;
    const int ty  = tid >> 5;
    const long rbase = (long)blockIdx.x * 64;

    const float4* Xv = reinterpret_cast<const float4*>(X + rbase * 128);
#pragma unroll
    for (int i = 0; i < 8; ++i) {
        int idx = tid + i * 256;
        xs[idx >> 5][idx & 31] = Xv[idx];
    }
    __syncthreads();

    float acc[8][4];
#pragma unroll
    for (int r = 0; r < 8; ++r)
#pragma unroll
        for (int c = 0; c < 4; ++c) acc[r][c] = 0.0f;

    const float4* Wv = reinterpret_cast<const float4*>(W);

#pragma unroll 1
    for (int k0 = 0; k0 < 32; ++k0) {
        float4 w0 = Wv[(k0 * 4 + 0) * 32 + tx];
        float4 w1 = Wv[(k0 * 4 + 1) * 32 + tx];
        float4 w2 = Wv[(k0 * 4 + 2) * 32 + tx];
        float4 w3 = Wv[(k0 * 4 + 3) * 32 + tx];
#pragma unroll
        for (int rr = 0; rr < 8; ++rr) {
            int row = rr * 8 + ty;
            float4 xv = xs[row][k0];
            acc[rr][0] += xv.x * w0.x + xv.y * w1.x + xv.z * w2.x + xv.w * w3.x;
            acc[rr][1] += xv.x * w0.y + xv.y * w1.y + xv.z * w2.y + xv.w * w3.y;
            acc[rr][2] += xv.x * w0.z + xv.y * w1.z + xv.z * w2.z + xv.w * w3.z;
            acc[rr][3] += xv.x * w0.w + xv.y * w1.w + xv.z * w2.w + xv.w * w3.w;
        }
    }

#pragma unroll
    for (int rr = 0; rr < 8; ++rr) {
        int row = rr * 8 + ty;
        ushort4 o;
        o.x = f2bf(acc[rr][0]); o.y = f2bf(acc[rr][1]);
        o.z = f2bf(acc[rr][2]); o.w = f2bf(acc[rr][3]);
        reinterpret_cast<ushort4*>(Hf + (rbase + row) * 128)[tx] = o;
    }
}

// ---------------- big path: two-level counting sort -----------------------
__global__ __launch_bounds__(256) void hist_coarse(const int* __restrict__ r0,
                                                   const int* __restrict__ r1,
                                                   int* __restrict__ cnt, int E) {
    __shared__ int h[NB];
    const int f = blockIdx.y, t = threadIdx.x;
    const int* rows = f ? r1 : r0;
    h[t] = 0;
    __syncthreads();
    const int base = blockIdx.x * EPB;
    for (int k = 0; k < EPB / 256; ++k) {
        int e = base + k * 256 + t;
        if (e < E) atomicAdd(&h[rows[e] >> 8], 1);
    }
    __syncthreads();
    if (h[t]) atomicAdd(&cnt[f * NB + t], h[t]);
}

// One block per filter: exclusive scan of 256 bucket counts.
__global__ __launch_bounds__(256) void scan_coarse(const int* __restrict__ cnt,
                                                   int* __restrict__ bbase,
                                                   int* __restrict__ bcur,
                                                   int* __restrict__ row_ptr,
                                                   int rp_stride, int BN, int E) {
    __shared__ int s[NB];
    const int f = blockIdx.x, t = threadIdx.x;
    int v = cnt[f * NB + t];
    s[t] = v;
    __syncthreads();
    for (int off = 1; off < NB; off <<= 1) {
        int u = (t >= off) ? s[t - off] : 0;
        __syncthreads();
        s[t] += u;
        __syncthreads();
    }
    int base = s[t] - v;
    bbase[f * NB + t] = base;
    bcur [f * NB + t] = base;
    if (t == NB - 1) row_ptr[(size_t)f * rp_stride + BN] = E;   // sentinel
}

// Partition edges into coarse buckets. Each block reserves a contiguous chunk
// per bucket so same-cache-line writes come from one block (one XCD).
__global__ __launch_bounds__(256) void partition(const int* __restrict__ r0,
                                                 const int* __restrict__ c0,
                                                 const float* __restrict__ v0,
                                                 const int* __restrict__ r1,
                                                 const int* __restrict__ c1,
                                                 const float* __restrict__ v1,
                                                 int* __restrict__ bcur,
                                                 uint* __restrict__ cvy,
                                                 uchar* __restrict__ cvr, int E) {
    __shared__ int h[NB];
    __shared__ int cur[NB];
    const int f = blockIdx.y, t = threadIdx.x;
    const int*   rows = f ? r1 : r0;
    const int*   cols = f ? c1 : c0;
    const float* vals = f ? v1 : v0;
    const int base = blockIdx.x * EPB;

    h[t] = 0;
    __syncthreads();
    for (int k = 0; k < EPB / 256; ++k) {
        int e = base + k * 256 + t;
        if (e < E) atomicAdd(&h[rows[e] >> 8], 1);
    }
    __syncthreads();
    cur[t] = atomicAdd(&bcur[f * NB + t], h[t]);    // chunk base for bucket t
    __syncthreads();

    uint*  yout = cvy + (size_t)f * E;
    uchar* rout = cvr + (size_t)f * E;
    for (int k = 0; k < EPB / 256; ++k) {
        int e = base + k * 256 + t;
        if (e < E) {
            int r = rows[e];
            int pos = atomicAdd(&cur[r >> 8], 1);
            yout[pos] = ((uint)cols[e] << 16) | (uint)f2bf(vals[e]);
            rout[pos] = (uchar)(r & 255);
        }
    }
}

// One block per (bucket, filter): sort recs by row within the bucket,
// emit final packed cv and per-row row_ptr. Writes stay in the block's
// ~16KB region -> L2 write-combined.
__global__ __launch_bounds__(256) void bucket_sort(const uint* __restrict__ cvy,
                                                   const uchar* __restrict__ cvr,
                                                   const int* __restrict__ bbase,
                                                   const int* __restrict__ bcur,
                                                   uint* __restrict__ cv,
                                                   int* __restrict__ row_ptr,
                                                   int rp_stride, int E) {
    __shared__ int h[NB];
    __shared__ int s[NB];
    __shared__ int curs[NB];
    const int f = blockIdx.y, b = blockIdx.x, t = threadIdx.x;
    const int start = bbase[f * NB + b];
    const int end   = bcur [f * NB + b];            // cursor == bucket end now
    const uint*  yin = cvy + (size_t)f * E;
    const uchar* rin = cvr + (size_t)f * E;

    h[t] = 0;
    __syncthreads();
    for (int i = start + t; i < end; i += 256)
        atomicAdd(&h[rin[i]], 1);
    __syncthreads();

    int v = h[t];
    s[t] = v;
    __syncthreads();
    for (int off = 1; off < NB; off <<= 1) {
        int u = (t >= off) ? s[t - off] : 0;
        __syncthreads();
        s[t] += u;
        __syncthreads();
    }
    int rowbase = start + s[t] - v;                 // filter-local cv offset
    row_ptr[(size_t)f * rp_stride + b * 256 + t] = rowbase;
    curs[t] = rowbase;
    __syncthreads();

    uint* outp = cv + (size_t)f * E;
    for (int i = start + t; i < end; i += 256) {
        int pos = atomicAdd(&curs[rin[i]], 1);
        outp[pos] = yin[i];
    }
}

// ---------------- fallback path (round-5): flat hist/scan/permute ---------
__global__ __launch_bounds__(256) void hist2(const int* __restrict__ r0,
                                             const int* __restrict__ r1,
                                             int* __restrict__ cnt, int E, int BN) {
    int e = blockIdx.x * 256 + threadIdx.x;
    const int* rows = blockIdx.y ? r1 : r0;
    if (e < E) atomicAdd(&cnt[(size_t)blockIdx.y * BN + rows[e]], 1);
}

__global__ __launch_bounds__(256) void scan2(int* __restrict__ cnt,
                                             int* __restrict__ row_ptr,
                                             int n, int rp_stride) {
    __shared__ int ssum[256];
    int* counts = cnt + (size_t)blockIdx.x * n;
    int* rp     = row_ptr + (size_t)blockIdx.x * rp_stride;
    const int t = threadIdx.x;
    const int chunk = n / 256;
    const int base = t * chunk;
    const int4* c4 = reinterpret_cast<const int4*>(counts + base);
    int s = 0;
#pragma unroll 4
    for (int i = 0; i < chunk / 4; ++i) {
        int4 v = c4[i];
        s += v.x + v.y + v.z + v.w;
    }
    ssum[t] = s;
    __syncthreads();
    for (int off = 1; off < 256; off <<= 1) {
        int u = (t >= off) ? ssum[t - off] : 0;
        __syncthreads();
        ssum[t] += u;
        __syncthreads();
    }
    int run = ssum[t] - s;
    int4* rp4 = reinterpret_cast<int4*>(rp + base);
    int4* cu4 = reinterpret_cast<int4*>(counts + base);
#pragma unroll 4
    for (int i = 0; i < chunk / 4; ++i) {
        int4 v = c4[i];
        int4 p;
        p.x = run; run += v.x;
        p.y = run; run += v.y;
        p.z = run; run += v.z;
        p.w = run; run += v.w;
        rp4[i] = p;
        cu4[i] = p;
    }
    if (t == 255) rp[n] = run;
}

__global__ __launch_bounds__(256) void permute2(const int* __restrict__ r0,
                                                const int* __restrict__ c0,
                                                const float* __restrict__ v0,
                                                const int* __restrict__ r1,
                                                const int* __restrict__ c1,
                                                const float* __restrict__ v1,
                                                int* __restrict__ cursor,
                                                uint* __restrict__ cv, int E, int BN) {
    int f = blockIdx.y;
    const int*   rows = f ? r1 : r0;
    const int*   cols = f ? c1 : c0;
    const float* vals = f ? v1 : v0;
    int e = blockIdx.x * 256 + threadIdx.x;
    if (e < E) {
        int r = rows[e];
        int pos = atomicAdd(&cursor[(size_t)f * BN + r], 1);
        cv[(size_t)f * E + pos] = ((uint)cols[e] << 16) | (uint)f2bf(vals[e]);
    }
}

// ---------------- fused gather: out[r] = relu(sum_A0 + sum_A1) ------------
__device__ __forceinline__ void fma4(float4& a, float v, ushort4 h) {
    a.x = fmaf(v, bf2f(h.x), a.x);
    a.y = fmaf(v, bf2f(h.y), a.y);
    a.z = fmaf(v, bf2f(h.z), a.z);
    a.w = fmaf(v, bf2f(h.w), a.w);
}

__global__ __launch_bounds__(256) void gather_fused(const int* __restrict__ row_ptr,
                                                    int rp_stride,
                                                    const uint* __restrict__ cv, int E,
                                                    const ushort* __restrict__ H, int BN,
                                                    float* __restrict__ out) {
    const int half = threadIdx.x >> 5;              // 0..7
    const int sub  = threadIdx.x & 31;              // col4 slot
    const int r = blockIdx.x * 8 + half;

    float4 a0 = make_float4(0.f, 0.f, 0.f, 0.f);
    float4 a1 = make_float4(0.f, 0.f, 0.f, 0.f);

#pragma unroll
    for (int f = 0; f < 2; ++f) {
        const int*    rp  = row_ptr + (size_t)f * rp_stride;
        const uint*   cvf = cv + (size_t)f * E;
        const ushort* Hf  = H + (size_t)f * BN * 128;
        int e = rp[r];
        const int t = rp[r + 1];
        for (; e + 3 < t; e += 4) {
            uint p0 = cvf[e], p1 = cvf[e + 1], p2 = cvf[e + 2], p3 = cvf[e + 3];
            ushort4 h0 = reinterpret_cast<const ushort4*>(Hf + (size_t)(p0 >> 16) * 128)[sub];
            ushort4 h1 = reinterpret_cast<const ushort4*>(Hf + (size_t)(p1 >> 16) * 128)[sub];
            ushort4 h2 = reinterpret_cast<const ushort4*>(Hf + (size_t)(p2 >> 16) * 128)[sub];
            ushort4 h3 = reinterpret_cast<const ushort4*>(Hf + (size_t)(p3 >> 16) * 128)[sub];
            fma4(a0, __uint_as_float(p0 << 16), h0);
            fma4(a1, __uint_as_float(p1 << 16), h1);
            fma4(a0, __uint_as_float(p2 << 16), h2);
            fma4(a1, __uint_as_float(p3 << 16), h3);
        }
        for (; e < t; ++e) {
            uint p0 = cvf[e];
            ushort4 h0 = reinterpret_cast<const ushort4*>(Hf + (size_t)(p0 >> 16) * 128)[sub];
            fma4(a0, __uint_as_float(p0 << 16), h0);
        }
    }

    float4 o;
    o.x = fmaxf(a0.x + a1.x, 0.0f);
    o.y = fmaxf(a0.y + a1.y, 0.0f);
    o.z = fmaxf(a0.z + a1.z, 0.0f);
    o.w = fmaxf(a0.w + a1.w, 0.0f);
    reinterpret_cast<float4*>(out)[(size_t)r * 32 + sub] = o;
}

extern "C" void kernel_launch(void* const* d_in, const int* in_sizes, int n_in,
                              void* d_out, int out_size, void* d_ws, size_t ws_size,
                              hipStream_t stream) {
    const float* X     = (const float*)d_in[0];
    const float* W0    = (const float*)d_in[1];
    const float* W1    = (const float*)d_in[2];
    const int*   rows0 = (const int*)d_in[3];
    const int*   cols0 = (const int*)d_in[4];
    const float* vals0 = (const float*)d_in[5];
    const int*   rows1 = (const int*)d_in[6];
    const int*   cols1 = (const int*)d_in[7];
    const float* vals1 = (const float*)d_in[8];
    float* out = (float*)d_out;

    const int BN = in_sizes[0] / 128;               // 65536
    const int E  = in_sizes[3];                     // 1048576
    const int rp_stride = BN + 16;

    // Common workspace: H | cv | row_ptr | EXTRA
    char* ws = (char*)d_ws;
    size_t off = 0;
    auto alloc = [&](size_t bytes) {
        void* p = ws + off;
        off = (off + bytes + 255) & ~(size_t)255;
        return p;
    };
    ushort* H       = (ushort*)alloc((size_t)2 * BN * 128 * sizeof(ushort)); // 32 MiB
    uint*   cv      = (uint*)  alloc((size_t)2 * E * sizeof(uint));          //  8 MiB
    int*    row_ptr = (int*)   alloc((size_t)2 * rp_stride * sizeof(int));

    const size_t common = off;
    const size_t need_big   = common + (size_t)2 * E * sizeof(uint)   // cvy
                                     + (size_t)2 * E * sizeof(uchar)  // cvr
                                     + 3 * (size_t)2 * NB * sizeof(int) + 1024;
    const size_t need_small = common + (size_t)2 * BN * sizeof(int) + 256;

    const int gemm_blocks = BN / 64;                // 1024
    const int gath_blocks = BN / 8;                 // 8192

    gemm_xw_bf16<<<dim3(gemm_blocks, 2), 256, 0, stream>>>(X, W0, W1, H, BN);

    if (ws_size >= need_big) {
        uint*  cvy   = (uint*) alloc((size_t)2 * E * sizeof(uint));
        uchar* cvr   = (uchar*)alloc((size_t)2 * E * sizeof(uchar));
        int*   cnt   = (int*)  alloc((size_t)2 * NB * sizeof(int));
        int*   bbase = (int*)  alloc((size_t)2 * NB * sizeof(int));
        int*   bcur  = (int*)  alloc((size_t)2 * NB * sizeof(int));

        const int part_blocks = (E + EPB - 1) / EPB;            // 128
        hipMemsetAsync(cnt, 0, (size_t)2 * NB * sizeof(int), stream);
        hist_coarse<<<dim3(part_blocks, 2), 256, 0, stream>>>(rows0, rows1, cnt, E);
        scan_coarse<<<2, 256, 0, stream>>>(cnt, bbase, bcur, row_ptr, rp_stride, BN, E);
        partition<<<dim3(part_blocks, 2), 256, 0, stream>>>(rows0, cols0, vals0,
                                                            rows1, cols1, vals1,
                                                            bcur, cvy, cvr, E);
        bucket_sort<<<dim3(NB, 2), 256, 0, stream>>>(cvy, cvr, bbase, bcur,
                                                     cv, row_ptr, rp_stride, E);
    } else {
        // round-5 fallback: flat 65536-bin counting sort
        int* cursor = (int*)alloc((size_t)2 * BN * sizeof(int));
        const int edge_blocks = (E + 255) / 256;
        hipMemsetAsync(cursor, 0, (size_t)2 * BN * sizeof(int), stream);
        hist2<<<dim3(edge_blocks, 2), 256, 0, stream>>>(rows0, rows1, cursor, E, BN);
        scan2<<<2, 256, 0, stream>>>(cursor, row_ptr, BN, rp_stride);
        permute2<<<dim3(edge_blocks, 2), 256, 0, stream>>>(rows0, cols0, vals0,
                                                           rows1, cols1, vals1,
                                                           cursor, cv, E, BN);
    }

    gather_fused<<<gath_blocks, 256, 0, stream>>>(row_ptr, rp_stride, cv, E, H, BN, out);
}

// Round 7
// 179.117 us; speedup vs baseline: 20.0934x; 1.1847x over previous
//
#include <hip/hip_runtime.h>

// GCN layer: out = relu( A0 @ (X W0) + A1 @ (X W1) )
//   X: [65536,128] fp32, W: [128,128] fp32, A*: COO (rows,cols,vals), E=1M each.
//
// Round 7: (a) fp32 vector GEMM -> bf16 MFMA GEMM (split-X hi/lo for accuracy,
// both filters per block, W pre-swizzled to fragment layout); (b) gather
// unrolled 8-deep with 4 accumulators (latency-bound per round-6 counters:
// VALU 34%, HBM 44%, occ 71% -- nothing saturated). Sort pipeline unchanged.

typedef unsigned int   uint;
typedef unsigned short ushort;
typedef unsigned char  uchar;
typedef float f32x4 __attribute__((ext_vector_type(4)));
typedef int   i32x4 __attribute__((ext_vector_type(4)));

constexpr int NB  = 256;   // coarse buckets: row >> 8 (BN=65536)
constexpr int EPB = 8192;  // edges per partition/hist block

__device__ __forceinline__ ushort f2bf(float f) {      // fp32 -> bf16 RNE
    uint u = __float_as_uint(f);
    u += 0x7fffu + ((u >> 16) & 1u);
    return (ushort)(u >> 16);
}
__device__ __forceinline__ float bf2f(ushort h) {      // bf16 -> fp32 (exact)
    return __uint_as_float((uint)h << 16);
}

// MFMA D-write hazard fence: data-dependent s_nops so the VALU read of acc
// can never be scheduled into the MFMA write shadow.
#define ACC_FENCE(a) asm volatile("s_nop 7\n\ts_nop 7" : "+v"(a))

// ---- W pre-swizzle: B-fragment layout for mfma_f32_16x16x32_bf16 ---------
// frag (f,ct,kt): lane l, j=0..7 holds W[f][kt*32+(l>>4)*8+j][ct*16+(l&15)]
__global__ __launch_bounds__(64) void w_swz(const float* __restrict__ W0,
                                            const float* __restrict__ W1,
                                            uint4* __restrict__ Wswz) {
    const int bx = blockIdx.x;            // 0..63
    const int f  = bx >> 5;
    const int ct = (bx >> 2) & 7;
    const int kt = bx & 3;
    const int l  = threadIdx.x;           // 0..63
    const float* W = f ? W1 : W0;
    const int kbase = kt * 32 + (l >> 4) * 8;
    const int col   = ct * 16 + (l & 15);
    ushort h[8];
#pragma unroll
    for (int j = 0; j < 8; ++j)
        h[j] = f2bf(W[(kbase + j) * 128 + col]);
    uint4 o;
    o.x = (uint)h[0] | ((uint)h[1] << 16);
    o.y = (uint)h[2] | ((uint)h[3] << 16);
    o.z = (uint)h[4] | ((uint)h[5] << 16);
    o.w = (uint)h[6] | ((uint)h[7] << 16);
    Wswz[((f * 8 + ct) * 4 + kt) * 64 + l] = o;
}

// ---- MFMA GEMM: H_f = X @ W_f (both filters), bf16 out, split-X accuracy --
__global__ __launch_bounds__(256) void gemm_mfma(const float* __restrict__ X,
                                                 const i32x4* __restrict__ Wswz,
                                                 ushort* __restrict__ H, int BN) {
    __shared__ ushort xs_hi[64][136];     // +8 pad: A-frag ds_read 2-way (free)
    __shared__ ushort xs_lo[64][136];
    const int tid = threadIdx.x;
    const int l = tid & 63;
    const int w = tid >> 6;               // wave 0..3 -> rows w*16..+16
    const long rbase = (long)blockIdx.x * 64;

    const float4* Xv = reinterpret_cast<const float4*>(X + rbase * 128);
#pragma unroll
    for (int i = 0; i < 8; ++i) {
        int idx = i * 256 + tid;          // 0..2047
        int row = idx >> 5, c4 = idx & 31;
        float4 v = Xv[idx];
        ushort4 hi, lo;
        hi.x = f2bf(v.x); lo.x = f2bf(v.x - bf2f(hi.x));
        hi.y = f2bf(v.y); lo.y = f2bf(v.y - bf2f(hi.y));
        hi.z = f2bf(v.z); lo.z = f2bf(v.z - bf2f(hi.z));
        hi.w = f2bf(v.w); lo.w = f2bf(v.w - bf2f(hi.w));
        *reinterpret_cast<ushort4*>(&xs_hi[row][c4 * 4]) = hi;
        *reinterpret_cast<ushort4*>(&xs_lo[row][c4 * 4]) = lo;
    }
    __syncthreads();

    // A frags: row = w*16 + (l&15), k = kt*32 + (l>>4)*8 + j (k-contiguous;
    // any k-permutation is harmless as long as A and B agree -- they do).
    i32x4 a_hi[4], a_lo[4];
    const int arow = w * 16 + (l & 15);
    const int kb = (l >> 4) * 8;
#pragma unroll
    for (int kt = 0; kt < 4; ++kt) {
        a_hi[kt] = *reinterpret_cast<const i32x4*>(&xs_hi[arow][kt * 32 + kb]);
        a_lo[kt] = *reinterpret_cast<const i32x4*>(&xs_lo[arow][kt * 32 + kb]);
    }

    f32x4 acc[2][8];
#pragma unroll
    for (int f = 0; f < 2; ++f)
#pragma unroll
        for (int ct = 0; ct < 8; ++ct)
            acc[f][ct] = (f32x4)0.0f;

#pragma unroll
    for (int ct = 0; ct < 8; ++ct)
#pragma unroll
        for (int f = 0; f < 2; ++f)
#pragma unroll
            for (int kt = 0; kt < 4; ++kt) {
                i32x4 b = Wswz[((f * 8 + ct) * 4 + kt) * 64 + l];
                asm volatile("v_mfma_f32_16x16x32_bf16 %0, %1, %2, %0"
                             : "+v"(acc[f][ct]) : "v"(a_hi[kt]), "v"(b));
                asm volatile("v_mfma_f32_16x16x32_bf16 %0, %1, %2, %0"
                             : "+v"(acc[f][ct]) : "v"(a_lo[kt]), "v"(b));
            }

    // D layout (HW-verified m89/m91): col = l&15, row = (l>>4)*4 + reg
#pragma unroll
    for (int ct = 0; ct < 8; ++ct)
#pragma unroll
        for (int f = 0; f < 2; ++f) {
            f32x4 a = acc[f][ct];
            ACC_FENCE(a);
            ushort* Hf = H + (size_t)f * BN * 128;
            size_t base = (size_t)(rbase + w * 16 + (l >> 4) * 4) * 128
                        + ct * 16 + (l & 15);
            Hf[base]       = f2bf(a.x);
            Hf[base + 128] = f2bf(a.y);
            Hf[base + 256] = f2bf(a.z);
            Hf[base + 384] = f2bf(a.w);
        }
}

// ---------------- big path: two-level counting sort -----------------------
__global__ __launch_bounds__(256) void hist_coarse(const int* __restrict__ r0,
                                                   const int* __restrict__ r1,
                                                   int* __restrict__ cnt, int E) {
    __shared__ int h[NB];
    const int f = blockIdx.y, t = threadIdx.x;
    const int* rows = f ? r1 : r0;
    h[t] = 0;
    __syncthreads();
    const int base = blockIdx.x * EPB;
    for (int k = 0; k < EPB / 256; ++k) {
        int e = base + k * 256 + t;
        if (e < E) atomicAdd(&h[rows[e] >> 8], 1);
    }
    __syncthreads();
    if (h[t]) atomicAdd(&cnt[f * NB + t], h[t]);
}

__global__ __launch_bounds__(256) void scan_coarse(const int* __restrict__ cnt,
                                                   int* __restrict__ bbase,
                                                   int* __restrict__ bcur,
                                                   int* __restrict__ row_ptr,
                                                   int rp_stride, int BN, int E) {
    __shared__ int s[NB];
    const int f = blockIdx.x, t = threadIdx.x;
    int v = cnt[f * NB + t];
    s[t] = v;
    __syncthreads();
    for (int off = 1; off < NB; off <<= 1) {
        int u = (t >= off) ? s[t - off] : 0;
        __syncthreads();
        s[t] += u;
        __syncthreads();
    }
    int base = s[t] - v;
    bbase[f * NB + t] = base;
    bcur [f * NB + t] = base;
    if (t == NB - 1) row_ptr[(size_t)f * rp_stride + BN] = E;
}

__global__ __launch_bounds__(256) void partition(const int* __restrict__ r0,
                                                 const int* __restrict__ c0,
                                                 const float* __restrict__ v0,
                                                 const int* __restrict__ r1,
                                                 const int* __restrict__ c1,
                                                 const float* __restrict__ v1,
                                                 int* __restrict__ bcur,
                                                 uint* __restrict__ cvy,
                                                 uchar* __restrict__ cvr, int E) {
    __shared__ int h[NB];
    __shared__ int cur[NB];
    const int f = blockIdx.y, t = threadIdx.x;
    const int*   rows = f ? r1 : r0;
    const int*   cols = f ? c1 : c0;
    const float* vals = f ? v1 : v0;
    const int base = blockIdx.x * EPB;

    h[t] = 0;
    __syncthreads();
    for (int k = 0; k < EPB / 256; ++k) {
        int e = base + k * 256 + t;
        if (e < E) atomicAdd(&h[rows[e] >> 8], 1);
    }
    __syncthreads();
    cur[t] = atomicAdd(&bcur[f * NB + t], h[t]);
    __syncthreads();

    uint*  yout = cvy + (size_t)f * E;
    uchar* rout = cvr + (size_t)f * E;
    for (int k = 0; k < EPB / 256; ++k) {
        int e = base + k * 256 + t;
        if (e < E) {
            int r = rows[e];
            int pos = atomicAdd(&cur[r >> 8], 1);
            yout[pos] = ((uint)cols[e] << 16) | (uint)f2bf(vals[e]);
            rout[pos] = (uchar)(r & 255);
        }
    }
}

__global__ __launch_bounds__(256) void bucket_sort(const uint* __restrict__ cvy,
                                                   const uchar* __restrict__ cvr,
                                                   const int* __restrict__ bbase,
                                                   const int* __restrict__ bcur,
                                                   uint* __restrict__ cv,
                                                   int* __restrict__ row_ptr,
                                                   int rp_stride, int E) {
    __shared__ int h[NB];
    __shared__ int s[NB];
    __shared__ int curs[NB];
    const int f = blockIdx.y, b = blockIdx.x, t = threadIdx.x;
    const int start = bbase[f * NB + b];
    const int end   = bcur [f * NB + b];
    const uint*  yin = cvy + (size_t)f * E;
    const uchar* rin = cvr + (size_t)f * E;

    h[t] = 0;
    __syncthreads();
    for (int i = start + t; i < end; i += 256)
        atomicAdd(&h[rin[i]], 1);
    __syncthreads();

    int v = h[t];
    s[t] = v;
    __syncthreads();
    for (int off = 1; off < NB; off <<= 1) {
        int u = (t >= off) ? s[t - off] : 0;
        __syncthreads();
        s[t] += u;
        __syncthreads();
    }
    int rowbase = start + s[t] - v;
    row_ptr[(size_t)f * rp_stride + b * 256 + t] = rowbase;
    curs[t] = rowbase;
    __syncthreads();

    uint* outp = cv + (size_t)f * E;
    for (int i = start + t; i < end; i += 256) {
        int pos = atomicAdd(&curs[rin[i]], 1);
        outp[pos] = yin[i];
    }
}

// ---------------- fallback path (round-5 flat sort) -----------------------
__global__ __launch_bounds__(256) void hist2(const int* __restrict__ r0,
                                             const int* __restrict__ r1,
                                             int* __restrict__ cnt, int E, int BN) {
    int e = blockIdx.x * 256 + threadIdx.x;
    const int* rows = blockIdx.y ? r1 : r0;
    if (e < E) atomicAdd(&cnt[(size_t)blockIdx.y * BN + rows[e]], 1);
}

__global__ __launch_bounds__(256) void scan2(int* __restrict__ cnt,
                                             int* __restrict__ row_ptr,
                                             int n, int rp_stride) {
    __shared__ int ssum[256];
    int* counts = cnt + (size_t)blockIdx.x * n;
    int* rp     = row_ptr + (size_t)blockIdx.x * rp_stride;
    const int t = threadIdx.x;
    const int chunk = n / 256;
    const int base = t * chunk;
    const int4* c4 = reinterpret_cast<const int4*>(counts + base);
    int s = 0;
#pragma unroll 4
    for (int i = 0; i < chunk / 4; ++i) {
        int4 v = c4[i];
        s += v.x + v.y + v.z + v.w;
    }
    ssum[t] = s;
    __syncthreads();
    for (int off = 1; off < 256; off <<= 1) {
        int u = (t >= off) ? ssum[t - off] : 0;
        __syncthreads();
        ssum[t] += u;
        __syncthreads();
    }
    int run = ssum[t] - s;
    int4* rp4 = reinterpret_cast<int4*>(rp + base);
    int4* cu4 = reinterpret_cast<int4*>(counts + base);
#pragma unroll 4
    for (int i = 0; i < chunk / 4; ++i) {
        int4 v = c4[i];
        int4 p;
        p.x = run; run += v.x;
        p.y = run; run += v.y;
        p.z = run; run += v.z;
        p.w = run; run += v.w;
        rp4[i] = p;
        cu4[i] = p;
    }
    if (t == 255) rp[n] = run;
}

__global__ __launch_bounds__(256) void permute2(const int* __restrict__ r0,
                                                const int* __restrict__ c0,
                                                const float* __restrict__ v0,
                                                const int* __restrict__ r1,
                                                const int* __restrict__ c1,
                                                const float* __restrict__ v1,
                                                int* __restrict__ cursor,
                                                uint* __restrict__ cv, int E, int BN) {
    int f = blockIdx.y;
    const int*   rows = f ? r1 : r0;
    const int*   cols = f ? c1 : c0;
    const float* vals = f ? v1 : v0;
    int e = blockIdx.x * 256 + threadIdx.x;
    if (e < E) {
        int r = rows[e];
        int pos = atomicAdd(&cursor[(size_t)f * BN + r], 1);
        cv[(size_t)f * E + pos] = ((uint)cols[e] << 16) | (uint)f2bf(vals[e]);
    }
}

// ---------------- fused gather: out[r] = relu(sum_A0 + sum_A1) ------------
__device__ __forceinline__ void fma4(float4& a, float v, ushort4 h) {
    a.x = fmaf(v, bf2f(h.x), a.x);
    a.y = fmaf(v, bf2f(h.y), a.y);
    a.z = fmaf(v, bf2f(h.z), a.z);
    a.w = fmaf(v, bf2f(h.w), a.w);
}

__global__ __launch_bounds__(256) void gather_fused(const int* __restrict__ row_ptr,
                                                    int rp_stride,
                                                    const uint* __restrict__ cv, int E,
                                                    const ushort* __restrict__ H, int BN,
                                                    float* __restrict__ out) {
    const int half = threadIdx.x >> 5;
    const int sub  = threadIdx.x & 31;
    const int r = blockIdx.x * 8 + half;

    float4 a0 = make_float4(0.f, 0.f, 0.f, 0.f);
    float4 a1 = make_float4(0.f, 0.f, 0.f, 0.f);
    float4 a2 = make_float4(0.f, 0.f, 0.f, 0.f);
    float4 a3 = make_float4(0.f, 0.f, 0.f, 0.f);

#pragma unroll
    for (int f = 0; f < 2; ++f) {
        const int*    rp  = row_ptr + (size_t)f * rp_stride;
        const uint*   cvf = cv + (size_t)f * E;
        const ushort* Hf  = H + (size_t)f * BN * 128;
        int e = rp[r];
        const int t = rp[r + 1];
        for (; e + 7 < t; e += 8) {
            uint p0 = cvf[e],     p1 = cvf[e + 1], p2 = cvf[e + 2], p3 = cvf[e + 3];
            uint p4 = cvf[e + 4], p5 = cvf[e + 5], p6 = cvf[e + 6], p7 = cvf[e + 7];
            ushort4 h0 = reinterpret_cast<const ushort4*>(Hf + (size_t)(p0 >> 16) * 128)[sub];
            ushort4 h1 = reinterpret_cast<const ushort4*>(Hf + (size_t)(p1 >> 16) * 128)[sub];
            ushort4 h2 = reinterpret_cast<const ushort4*>(Hf + (size_t)(p2 >> 16) * 128)[sub];
            ushort4 h3 = reinterpret_cast<const ushort4*>(Hf + (size_t)(p3 >> 16) * 128)[sub];
            ushort4 h4 = reinterpret_cast<const ushort4*>(Hf + (size_t)(p4 >> 16) * 128)[sub];
            ushort4 h5 = reinterpret_cast<const ushort4*>(Hf + (size_t)(p5 >> 16) * 128)[sub];
            ushort4 h6 = reinterpret_cast<const ushort4*>(Hf + (size_t)(p6 >> 16) * 128)[sub];
            ushort4 h7 = reinterpret_cast<const ushort4*>(Hf + (size_t)(p7 >> 16) * 128)[sub];
            fma4(a0, __uint_as_float(p0 << 16), h0);
            fma4(a1, __uint_as_float(p1 << 16), h1);
            fma4(a2, __uint_as_float(p2 << 16), h2);
            fma4(a3, __uint_as_float(p3 << 16), h3);
            fma4(a0, __uint_as_float(p4 << 16), h4);
            fma4(a1, __uint_as_float(p5 << 16), h5);
            fma4(a2, __uint_as_float(p6 << 16), h6);
            fma4(a3, __uint_as_float(p7 << 16), h7);
        }
        for (; e + 3 < t; e += 4) {
            uint p0 = cvf[e], p1 = cvf[e + 1], p2 = cvf[e + 2], p3 = cvf[e + 3];
            ushort4 h0 = reinterpret_cast<const ushort4*>(Hf + (size_t)(p0 >> 16) * 128)[sub];
            ushort4 h1 = reinterpret_cast<const ushort4*>(Hf + (size_t)(p1 >> 16) * 128)[sub];
            ushort4 h2 = reinterpret_cast<const ushort4*>(Hf + (size_t)(p2 >> 16) * 128)[sub];
            ushort4 h3 = reinterpret_cast<const ushort4*>(Hf + (size_t)(p3 >> 16) * 128)[sub];
            fma4(a0, __uint_as_float(p0 << 16), h0);
            fma4(a1, __uint_as_float(p1 << 16), h1);
            fma4(a2, __uint_as_float(p2 << 16), h2);
            fma4(a3, __uint_as_float(p3 << 16), h3);
        }
        for (; e < t; ++e) {
            uint p0 = cvf[e];
            ushort4 h0 = reinterpret_cast<const ushort4*>(Hf + (size_t)(p0 >> 16) * 128)[sub];
            fma4(a0, __uint_as_float(p0 << 16), h0);
        }
    }

    float4 o;
    o.x = fmaxf((a0.x + a1.x) + (a2.x + a3.x), 0.0f);
    o.y = fmaxf((a0.y + a1.y) + (a2.y + a3.y), 0.0f);
    o.z = fmaxf((a0.z + a1.z) + (a2.z + a3.z), 0.0f);
    o.w = fmaxf((a0.w + a1.w) + (a2.w + a3.w), 0.0f);
    reinterpret_cast<float4*>(out)[(size_t)r * 32 + sub] = o;
}

extern "C" void kernel_launch(void* const* d_in, const int* in_sizes, int n_in,
                              void* d_out, int out_size, void* d_ws, size_t ws_size,
                              hipStream_t stream) {
    const float* X     = (const float*)d_in[0];
    const float* W0    = (const float*)d_in[1];
    const float* W1    = (const float*)d_in[2];
    const int*   rows0 = (const int*)d_in[3];
    const int*   cols0 = (const int*)d_in[4];
    const float* vals0 = (const float*)d_in[5];
    const int*   rows1 = (const int*)d_in[6];
    const int*   cols1 = (const int*)d_in[7];
    const float* vals1 = (const float*)d_in[8];
    float* out = (float*)d_out;

    const int BN = in_sizes[0] / 128;               // 65536
    const int E  = in_sizes[3];                     // 1048576
    const int rp_stride = BN + 16;

    char* ws = (char*)d_ws;
    size_t off = 0;
    auto alloc = [&](size_t bytes) {
        void* p = ws + off;
        off = (off + bytes + 255) & ~(size_t)255;
        return p;
    };
    ushort* H       = (ushort*)alloc((size_t)2 * BN * 128 * sizeof(ushort)); // 32 MiB
    uint*   cv      = (uint*)  alloc((size_t)2 * E * sizeof(uint));          //  8 MiB
    int*    row_ptr = (int*)   alloc((size_t)2 * rp_stride * sizeof(int));
    uint4*  Wswz    = (uint4*) alloc((size_t)2 * 128 * 128 * sizeof(ushort)); // 128 KiB

    const size_t need_big = off + (size_t)2 * E * sizeof(uint)
                                + (size_t)2 * E * sizeof(uchar)
                                + 3 * (size_t)2 * NB * sizeof(int) + 1024;

    const int gath_blocks = BN / 8;                 // 8192

    w_swz<<<64, 64, 0, stream>>>(W0, W1, Wswz);
    gemm_mfma<<<BN / 64, 256, 0, stream>>>(X, (const i32x4*)Wswz, H, BN);

    if (ws_size >= need_big && BN == 65536) {
        uint*  cvy   = (uint*) alloc((size_t)2 * E * sizeof(uint));
        uchar* cvr   = (uchar*)alloc((size_t)2 * E * sizeof(uchar));
        int*   cnt   = (int*)  alloc((size_t)2 * NB * sizeof(int));
        int*   bbase = (int*)  alloc((size_t)2 * NB * sizeof(int));
        int*   bcur  = (int*)  alloc((size_t)2 * NB * sizeof(int));

        const int part_blocks = (E + EPB - 1) / EPB;            // 128
        hipMemsetAsync(cnt, 0, (size_t)2 * NB * sizeof(int), stream);
        hist_coarse<<<dim3(part_blocks, 2), 256, 0, stream>>>(rows0, rows1, cnt, E);
        scan_coarse<<<2, 256, 0, stream>>>(cnt, bbase, bcur, row_ptr, rp_stride, BN, E);
        partition<<<dim3(part_blocks, 2), 256, 0, stream>>>(rows0, cols0, vals0,
                                                            rows1, cols1, vals1,
                                                            bcur, cvy, cvr, E);
        bucket_sort<<<dim3(NB, 2), 256, 0, stream>>>(cvy, cvr, bbase, bcur,
                                                     cv, row_ptr, rp_stride, E);
    } else {
        int* cursor = (int*)alloc((size_t)2 * BN * sizeof(int));
        const int edge_blocks = (E + 255) / 256;
        hipMemsetAsync(cursor, 0, (size_t)2 * BN * sizeof(int), stream);
        hist2<<<dim3(edge_blocks, 2), 256, 0, stream>>>(rows0, rows1, cursor, E, BN);
        scan2<<<2, 256, 0, stream>>>(cursor, row_ptr, BN, rp_stride);
        permute2<<<dim3(edge_blocks, 2), 256, 0, stream>>>(rows0, cols0, vals0,
                                                           rows1, cols1, vals1,
                                                           cursor, cv, E, BN);
    }

    gather_fused<<<gath_blocks, 256, 0, stream>>>(row_ptr, rp_stride, cv, E, H, BN, out);
}